// Round 2
// baseline (378.871 us; speedup 1.0000x reference)
//
#include <hip/hip_runtime.h>

// AttentionGate: out[b,cf,v] = x[b,cf,v] * sigmoid(Wpsi · relu(Wg·g[b,:,v] + Wx·x[b,:,v]))
// B=2, CF=CG=64, CI=32, SPAT=64^3. fp32.
//
// R4: software-pipeline play. R2 (50% occ) ≈ R3 (70% occ) ≈ 110-114 µs proved
// occupancy is NOT the lever. Little's law on R3's counters: 2.95 TB/s @ ~900cy
// => only ~4 KB/CU in flight (~10% of what resident waves could hold). The
// unroll-4 loop issues 8 loads, drains vmcnt, then runs a 512-cy FMA block with
// zero loads outstanding. Fix: explicit register double-buffer (GRP=8) —
// prefetch group i+1's 16 loads (4 KB/wave) BEFORE group i's 512 FMAs, ping-pong
// buffers with static indices (unroll 2 folds the parity branches; rule #20:
// no runtime-indexed register arrays). Body ~9 KB, I$-safe. launch_bounds(256,4)
// gives VGPR headroom (~90) for the pipeline; ~5 waves/SIMD.

#define SPAT 262144        // 64*64*64 voxels per (b,c) plane, 2^18
#define NVOX 524288        // B * SPAT
#define CIN  64
#define COUT 32
#define GRP  8             // channels per pipeline stage
#define NCG  (CIN / GRP)   // 8 stages

__global__ __launch_bounds__(256) void transpose_w(const float* __restrict__ Wg,
                                                   const float* __restrict__ Wx,
                                                   float* __restrict__ Wcat) {
    int idx = blockIdx.x * 256 + threadIdx.x;   // 0..4095
    int c = idx >> 6;
    int o = idx & 63;
    float v = (o < 32) ? Wg[o * CIN + c] : Wx[(o - 32) * CIN + c];
    Wcat[c * 64 + o] = v;
}

__global__ __launch_bounds__(256, 4) void gate_main(const float* __restrict__ x,
                                                    const float* __restrict__ g,
                                                    const float* __restrict__ Wcat,
                                                    const float* __restrict__ Wpsi,
                                                    float* __restrict__ out) {
    int p = blockIdx.x * 256 + threadIdx.x;     // voxel index 0..524287
    int b = p >> 18;                            // SPAT = 2^18
    int s = p & (SPAT - 1);

    const float* __restrict__ xp = x + (size_t)b * CIN * SPAT + s;
    const float* __restrict__ gp = g + (size_t)b * CIN * SPAT + s;

    float acc[COUT];
#pragma unroll
    for (int o = 0; o < COUT; ++o) acc[o] = 0.0f;

    float ga[GRP], xa[GRP], gb[GRP], xb[GRP];

    // prologue: stage group 0 into (ga, xa)
#pragma unroll
    for (int k = 0; k < GRP; ++k) {
        ga[k] = __builtin_nontemporal_load(gp + (size_t)k * SPAT);  // g read once
        xa[k] = xp[(size_t)k * SPAT];                               // x re-read in epilogue
    }

#pragma unroll 2
    for (int cg = 0; cg < NCG; ++cg) {
        if ((cg & 1) == 0) {
            // prefetch group cg+1 into (gb, xb), then consume (ga, xa)
            if (cg + 1 < NCG) {
#pragma unroll
                for (int k = 0; k < GRP; ++k) {
                    int c = (cg + 1) * GRP + k;
                    gb[k] = __builtin_nontemporal_load(gp + (size_t)c * SPAT);
                    xb[k] = xp[(size_t)c * SPAT];
                }
            }
#pragma unroll
            for (int k = 0; k < GRP; ++k) {
                int c = cg * GRP + k;
                const float* w = Wcat + c * 64;   // wave-uniform -> scalar loads
#pragma unroll
                for (int o = 0; o < COUT; ++o)
                    acc[o] = fmaf(w[o], ga[k], fmaf(w[32 + o], xa[k], acc[o]));
            }
        } else {
            // prefetch group cg+1 into (ga, xa), then consume (gb, xb)
            if (cg + 1 < NCG) {
#pragma unroll
                for (int k = 0; k < GRP; ++k) {
                    int c = (cg + 1) * GRP + k;
                    ga[k] = __builtin_nontemporal_load(gp + (size_t)c * SPAT);
                    xa[k] = xp[(size_t)c * SPAT];
                }
            }
#pragma unroll
            for (int k = 0; k < GRP; ++k) {
                int c = cg * GRP + k;
                const float* w = Wcat + c * 64;
#pragma unroll
                for (int o = 0; o < COUT; ++o)
                    acc[o] = fmaf(w[o], gb[k], fmaf(w[32 + o], xb[k], acc[o]));
            }
        }
    }

    float ps = 0.0f;
#pragma unroll
    for (int o = 0; o < COUT; ++o) {
        ps = fmaf(Wpsi[o], fmaxf(acc[o], 0.0f), ps);
    }
    float psi = 1.0f / (1.0f + __expf(-ps));

    float* __restrict__ op = out + (size_t)b * CIN * SPAT + s;
#pragma unroll 8
    for (int c = 0; c < CIN; ++c) {
        float xv = xp[(size_t)c * SPAT];        // L2/L3-warm re-read
        __builtin_nontemporal_store(xv * psi, op + (size_t)c * SPAT);  // write-once
    }
}

extern "C" void kernel_launch(void* const* d_in, const int* in_sizes, int n_in,
                              void* d_out, int out_size, void* d_ws, size_t ws_size,
                              hipStream_t stream) {
    const float* x    = (const float*)d_in[0];
    const float* g    = (const float*)d_in[1];
    const float* Wg   = (const float*)d_in[2];
    const float* Wx   = (const float*)d_in[3];
    const float* Wpsi = (const float*)d_in[4];
    float* out  = (float*)d_out;
    float* Wcat = (float*)d_ws;                 // 64*64 floats = 16 KB scratch

    transpose_w<<<16, 256, 0, stream>>>(Wg, Wx, Wcat);
    gate_main<<<NVOX / 256, 256, 0, stream>>>(x, g, Wcat, Wpsi, out);
}

// Round 3
// 323.468 us; speedup vs baseline: 1.1713x; 1.1713x over previous
//
#include <hip/hip_runtime.h>

// AttentionGate: out[b,cf,v] = x[b,cf,v] * sigmoid(Wpsi · relu(Wg·g[b,:,v] + Wx·x[b,:,v]))
// B=2, CF=CG=64, CI=32, SPAT=64^3. fp32.
//
// R5: load-width play. Evidence: R2 (8B/lane) 110µs ≈ R3 (4B/lane, 2x occ) 114µs;
// R4 manual pipeline regressed (spills, +19MB scratch writes). BW pins at ~3 TB/s
// = ~4KB/CU in flight. Channel stride is 2^20 B: a wave's adjacent-channel loads
// alias to one L1 set / one memory channel and serialize, capping useful in-flight
// requests per wave. Lever: payload per request. float4 (16B/lane, 1KB/wave/instr)
// quadruples in-flight bytes at the same request count. T=4 voxels/thread,
// acc = 32 x f32x4 (128 VGPR; 256 budget, ~3 waves/SIMD — R3 proved occupancy
// is not the limiter). Simple unroll-2 channel loop (compiler schedules it well;
// R4 proved manual ping-pong is counterproductive). g/out nontemporal; x cached
// for the epilogue re-read.

#define SPAT 262144        // 64*64*64 voxels per (b,c) plane, 2^18
#define NVOX 524288        // B * SPAT
#define CIN  64
#define COUT 32
#define S4   (SPAT / 4)    // float4 elements per (b,c) plane = 2^16

typedef float v4f __attribute__((ext_vector_type(4)));

__global__ __launch_bounds__(256) void transpose_w(const float* __restrict__ Wg,
                                                   const float* __restrict__ Wx,
                                                   float* __restrict__ Wcat) {
    int idx = blockIdx.x * 256 + threadIdx.x;   // 0..4095
    int c = idx >> 6;
    int o = idx & 63;
    float v = (o < 32) ? Wg[o * CIN + c] : Wx[(o - 32) * CIN + c];
    Wcat[c * 64 + o] = v;
}

__global__ __launch_bounds__(256) void gate_main(const v4f* __restrict__ x,
                                                 const v4f* __restrict__ g,
                                                 const float* __restrict__ Wcat,
                                                 const float* __restrict__ Wpsi,
                                                 v4f* __restrict__ out) {
    int p = blockIdx.x * 256 + threadIdx.x;     // quad index 0..131071
    int b = p >> 16;                            // S4 = 2^16
    int s = p & (S4 - 1);

    const v4f* __restrict__ xp = x + (size_t)b * CIN * S4 + s;
    const v4f* __restrict__ gp = g + (size_t)b * CIN * S4 + s;

    v4f acc[COUT];
#pragma unroll
    for (int o = 0; o < COUT; ++o) acc[o] = (v4f)(0.0f);

#pragma unroll 2
    for (int c = 0; c < CIN; ++c) {
        v4f gc = __builtin_nontemporal_load(gp + (size_t)c * S4);  // g read once
        v4f xc = xp[(size_t)c * S4];                               // x re-read in epilogue
        const float* w = Wcat + c * 64;         // wave-uniform -> scalar loads
#pragma unroll
        for (int o = 0; o < COUT; ++o) {
            float wg = w[o], wx = w[32 + o];
            acc[o].x = fmaf(wg, gc.x, fmaf(wx, xc.x, acc[o].x));
            acc[o].y = fmaf(wg, gc.y, fmaf(wx, xc.y, acc[o].y));
            acc[o].z = fmaf(wg, gc.z, fmaf(wx, xc.z, acc[o].z));
            acc[o].w = fmaf(wg, gc.w, fmaf(wx, xc.w, acc[o].w));
        }
    }

    v4f ps = (v4f)(0.0f);
#pragma unroll
    for (int o = 0; o < COUT; ++o) {
        float wp = Wpsi[o];
        ps.x = fmaf(wp, fmaxf(acc[o].x, 0.0f), ps.x);
        ps.y = fmaf(wp, fmaxf(acc[o].y, 0.0f), ps.y);
        ps.z = fmaf(wp, fmaxf(acc[o].z, 0.0f), ps.z);
        ps.w = fmaf(wp, fmaxf(acc[o].w, 0.0f), ps.w);
    }
    v4f psi;
    psi.x = 1.0f / (1.0f + __expf(-ps.x));
    psi.y = 1.0f / (1.0f + __expf(-ps.y));
    psi.z = 1.0f / (1.0f + __expf(-ps.z));
    psi.w = 1.0f / (1.0f + __expf(-ps.w));

    v4f* __restrict__ op = out + (size_t)b * CIN * S4 + s;
#pragma unroll 4
    for (int c = 0; c < CIN; ++c) {
        v4f xv = xp[(size_t)c * S4];            // L2/L3-warm re-read
        v4f ov;
        ov.x = xv.x * psi.x;
        ov.y = xv.y * psi.y;
        ov.z = xv.z * psi.z;
        ov.w = xv.w * psi.w;
        __builtin_nontemporal_store(ov, op + (size_t)c * S4);  // write-once
    }
}

extern "C" void kernel_launch(void* const* d_in, const int* in_sizes, int n_in,
                              void* d_out, int out_size, void* d_ws, size_t ws_size,
                              hipStream_t stream) {
    const float* x    = (const float*)d_in[0];
    const float* g    = (const float*)d_in[1];
    const float* Wg   = (const float*)d_in[2];
    const float* Wx   = (const float*)d_in[3];
    const float* Wpsi = (const float*)d_in[4];
    float* out  = (float*)d_out;
    float* Wcat = (float*)d_ws;                 // 64*64 floats = 16 KB scratch

    transpose_w<<<16, 256, 0, stream>>>(Wg, Wx, Wcat);
    gate_main<<<NVOX / 4 / 256, 256, 0, stream>>>((const v4f*)x, (const v4f*)g,
                                                  Wcat, Wpsi, (v4f*)out);
}